// Round 2
// baseline (315.506 us; speedup 1.0000x reference)
//
#include <hip/hip_runtime.h>

// ---------- types ----------
typedef __bf16 bf16x8 __attribute__((ext_vector_type(8)));
typedef float f32x4 __attribute__((ext_vector_type(4)));
typedef unsigned short u16x8 __attribute__((ext_vector_type(8)));

__device__ __forceinline__ unsigned short f2bf(float f) {
  union { float f; unsigned int u; } v; v.f = f;
  unsigned int r = v.u + 0x7FFFu + ((v.u >> 16) & 1u);
  return (unsigned short)(r >> 16);
}

// global -> LDS direct copy, 16B per lane; lds dst is wave-uniform base (+lane*16 by HW)
__device__ __forceinline__ void gload_lds16(const void* g, void* l) {
  __builtin_amdgcn_global_load_lds(
      (const __attribute__((address_space(1))) void*)g,
      (__attribute__((address_space(3))) void*)l, 16, 0, 0);
}

// ---------- conv: depthwise k=3 pad=1, three paths, bf16 out ----------
__global__ __launch_bounds__(256)
void conv3_kernel(const float* __restrict__ x,
                  const float* __restrict__ wq, const float* __restrict__ bq,
                  const float* __restrict__ wk, const float* __restrict__ bk,
                  const float* __restrict__ wv, const float* __restrict__ bv,
                  unsigned short* __restrict__ cq, unsigned short* __restrict__ ck,
                  unsigned short* __restrict__ cv)
{
  int idx = blockIdx.x * 256 + threadIdx.x;   // over B*S*D = 4194304
  int d = idx & 1023;
  int t = idx >> 10;          // b*2048+s
  int s = t & 2047;
  float xc = x[idx];
  float xm = (s > 0)    ? x[idx - 1024] : 0.0f;
  float xp = (s < 2047) ? x[idx + 1024] : 0.0f;
  cq[idx] = f2bf(xm * wq[d*3+0] + xc * wq[d*3+1] + xp * wq[d*3+2] + bq[d]);
  ck[idx] = f2bf(xm * wk[d*3+0] + xc * wk[d*3+1] + xp * wk[d*3+2] + bk[d]);
  cv[idx] = f2bf(xm * wv[d*3+0] + xc * wv[d*3+1] + xp * wv[d*3+2] + bv[d]);
}

// ---------- weight fp32 -> bf16 ----------
__global__ __launch_bounds__(256)
void cvt_w_kernel(const float* __restrict__ w0, const float* __restrict__ w1,
                  const float* __restrict__ w2, const float* __restrict__ w3,
                  unsigned short* __restrict__ o0, unsigned short* __restrict__ o1,
                  unsigned short* __restrict__ o2, unsigned short* __restrict__ o3)
{
  const float* src; unsigned short* dst;
  switch (blockIdx.y) {
    case 0: src = w0; dst = o0; break;
    case 1: src = w1; dst = o1; break;
    case 2: src = w2; dst = o2; break;
    default: src = w3; dst = o3; break;
  }
  int i = blockIdx.x * 1024 + threadIdx.x * 4;   // 1M elements per matrix
  float4 v = *(const float4*)(src + i);
  dst[i+0] = f2bf(v.x); dst[i+1] = f2bf(v.y);
  dst[i+2] = f2bf(v.z); dst[i+3] = f2bf(v.w);
}

// ---------- GEMM core: C[128x128] += A[bm..][K] * W[bn..][K]^T, K=1024, BK=32 ----------
__device__ __forceinline__ void gemm_tile_core(
    const unsigned short* __restrict__ A, const unsigned short* __restrict__ W,
    int bm, int bn, unsigned short* lA, unsigned short* lB, f32x4 acc[4][4])
{
  const int K = 1024;
  const int tid  = threadIdx.x;
  const int lane = tid & 63;
  const int w    = tid >> 6;            // wave 0..3
  const int lrow = lane & 15;
  const int lko  = (lane >> 4) * 8;     // k-offset within 32
  const int wm   = (w >> 1) * 64;
  const int wn   = (w & 1) * 64;

  #pragma unroll
  for (int i = 0; i < 4; i++)
    #pragma unroll
    for (int j = 0; j < 4; j++)
      acc[i][j] = f32x4{0.f, 0.f, 0.f, 0.f};

  for (int k0 = 0; k0 < K; k0 += 32) {
    // stage A and B tiles: 128x32 bf16 = 8KB each = 512 x 16B chunks; 4 chunks/row
    #pragma unroll
    for (int i = 0; i < 2; i++) {
      int ci  = (i * 4 + w) * 64 + lane;
      int row = ci >> 2;
      int kc  = (ci & 3) * 8;
      gload_lds16(A + (size_t)(bm + row) * K + (k0 + kc), lA + (size_t)(i*4 + w) * 512);
      gload_lds16(W + (size_t)(bn + row) * K + (k0 + kc), lB + (size_t)(i*4 + w) * 512);
    }
    __syncthreads();   // compiler drains vmcnt before barrier

    bf16x8 af[4], bfr[4];
    #pragma unroll
    for (int mt = 0; mt < 4; mt++)
      af[mt] = *(const bf16x8*)(lA + (wm + mt*16 + lrow) * 32 + lko);
    #pragma unroll
    for (int nt = 0; nt < 4; nt++)
      bfr[nt] = *(const bf16x8*)(lB + (wn + nt*16 + lrow) * 32 + lko);
    #pragma unroll
    for (int mt = 0; mt < 4; mt++)
      #pragma unroll
      for (int nt = 0; nt < 4; nt++)
        acc[mt][nt] = __builtin_amdgcn_mfma_f32_16x16x32_bf16(af[mt], bfr[nt], acc[mt][nt], 0, 0, 0);
    __syncthreads();
  }
}

// ---------- q/k/v projections, epilogue permutes to [B,H,S,64] bf16 ----------
__global__ __launch_bounds__(256)
void gemm_qkv_kernel(const unsigned short* __restrict__ cq, const unsigned short* __restrict__ ck,
                     const unsigned short* __restrict__ cv,
                     const unsigned short* __restrict__ wqb, const unsigned short* __restrict__ wkb,
                     const unsigned short* __restrict__ wvb,
                     const float* __restrict__ bq, const float* __restrict__ bk,
                     const float* __restrict__ bv,
                     unsigned short* __restrict__ qo, unsigned short* __restrict__ ko,
                     unsigned short* __restrict__ vo)
{
  __shared__ alignas(16) unsigned short lA[128 * 32];
  __shared__ alignas(16) unsigned short lB[128 * 32];
  int z = blockIdx.z;
  const unsigned short* A = (z == 0) ? cq : ((z == 1) ? ck : cv);
  const unsigned short* W = (z == 0) ? wqb : ((z == 1) ? wkb : wvb);
  const float* bias       = (z == 0) ? bq : ((z == 1) ? bk : bv);
  unsigned short* O       = (z == 0) ? qo : ((z == 1) ? ko : vo);
  float scale             = (z == 0) ? 0.125f : 1.0f;   // fold 1/sqrt(64) into Q (exact)

  int bm = blockIdx.y * 128, bn = blockIdx.x * 128;
  f32x4 acc[4][4];
  gemm_tile_core(A, W, bm, bn, lA, lB, acc);

  const int tid = threadIdx.x, lane = tid & 63, w = tid >> 6;
  const int lrow = lane & 15, lgrp = lane >> 4;
  const int wm = (w >> 1) * 64, wn = (w & 1) * 64;
  #pragma unroll
  for (int mt = 0; mt < 4; mt++) {
    #pragma unroll
    for (int nt = 0; nt < 4; nt++) {
      int gn = bn + wn + nt*16 + lrow;
      float bb = bias[gn];
      int h = gn >> 6, dk = gn & 63;
      #pragma unroll
      for (int i = 0; i < 4; i++) {
        int gm = bm + wm + mt*16 + lgrp*4 + i;     // b*2048+s
        int b = gm >> 11, s = gm & 2047;
        float val = (acc[mt][nt][i] + bb) * scale;
        O[((size_t)(b*16 + h) * 2048 + s) * 64 + dk] = f2bf(val);
      }
    }
  }
}

// ---------- final projection: f32 out ----------
__global__ __launch_bounds__(256)
void gemm_out_kernel(const unsigned short* __restrict__ A, const unsigned short* __restrict__ W,
                     const float* __restrict__ bias, float* __restrict__ Out)
{
  __shared__ alignas(16) unsigned short lA[128 * 32];
  __shared__ alignas(16) unsigned short lB[128 * 32];
  int bm = blockIdx.y * 128, bn = blockIdx.x * 128;
  f32x4 acc[4][4];
  gemm_tile_core(A, W, bm, bn, lA, lB, acc);

  const int tid = threadIdx.x, lane = tid & 63, w = tid >> 6;
  const int lrow = lane & 15, lgrp = lane >> 4;
  const int wm = (w >> 1) * 64, wn = (w & 1) * 64;
  #pragma unroll
  for (int mt = 0; mt < 4; mt++) {
    #pragma unroll
    for (int nt = 0; nt < 4; nt++) {
      int gn = bn + wn + nt*16 + lrow;
      float bb = bias[gn];
      #pragma unroll
      for (int i = 0; i < 4; i++) {
        int gm = bm + wm + mt*16 + lgrp*4 + i;
        Out[(size_t)gm * 1024 + gn] = acc[mt][nt][i] + bb;
      }
    }
  }
}

// ---------- V transpose: [B,H,S,64] -> [B,H,64,S] ----------
__global__ __launch_bounds__(256)
void vtrans_kernel(const unsigned short* __restrict__ V, unsigned short* __restrict__ Vt)
{
  __shared__ alignas(16) unsigned short T[64][72];   // 72: 16B-aligned rows + bank spread
  int bh = blockIdx.y, sb = blockIdx.x * 64;
  int t = threadIdx.x;
  {
    int s_l = t >> 2, d0 = (t & 3) * 16;
    const unsigned short* src = V + ((size_t)bh * 2048 + sb + s_l) * 64 + d0;
    u16x8 a = *(const u16x8*)src;
    u16x8 b = *(const u16x8*)(src + 8);
    *(u16x8*)&T[s_l][d0]     = a;
    *(u16x8*)&T[s_l][d0 + 8] = b;
  }
  __syncthreads();
  {
    int d_l = t >> 2, s0 = (t & 3) * 16;
    u16x8 o0, o1;
    #pragma unroll
    for (int j = 0; j < 8; j++) { o0[j] = T[s0 + j][d_l]; o1[j] = T[s0 + 8 + j][d_l]; }
    unsigned short* dst = Vt + ((size_t)bh * 64 + d_l) * 2048 + sb + s0;
    *(u16x8*)dst       = o0;
    *(u16x8*)(dst + 8) = o1;
  }
}

// ---------- flash attention: 8 waves x 16 q-rows = 128 q-rows/block; no barriers ----------
// K from global [bh][S][64]; V pre-transposed global [bh][64][S]; P via per-wave swizzled LDS.
__global__ __launch_bounds__(512)
void attn_kernel(const unsigned short* __restrict__ Q, const unsigned short* __restrict__ K,
                 const unsigned short* __restrict__ Vt, unsigned short* __restrict__ O)
{
  const int S = 2048;
  // XCD-aware decode: xcd = n&7 gets bh group 4*xcd..4*xcd+3 (heads' K/V stay in one XCD's L2)
  int n = blockIdx.x;
  int xcd = n & 7, r = n >> 3;
  int bh = (xcd << 2) | (r & 3);
  int qbase = (r >> 2) * 128;

  const int tid = threadIdx.x, lane = tid & 63, w = tid >> 6;   // 8 waves
  const int lrow = lane & 15, lgrp = lane >> 4;
  const unsigned short* Qh = Q  + (size_t)bh * S * 64;
  const unsigned short* Kh = K  + (size_t)bh * S * 64;
  const unsigned short* Vh = Vt + (size_t)bh * 64 * S;

  __shared__ alignas(16) unsigned short Pb[8][16][64];   // per-wave, XOR-swizzled cols

  bf16x8 qf[2];
  {
    const unsigned short* qp = Qh + (size_t)(qbase + w*16 + lrow) * 64 + lgrp * 8;
    qf[0] = *(const bf16x8*)qp;
    qf[1] = *(const bf16x8*)(qp + 32);
  }
  f32x4 oacc[4];
  #pragma unroll
  for (int i = 0; i < 4; i++) oacc[i] = f32x4{0.f, 0.f, 0.f, 0.f};
  float m_r[4] = {-1e30f, -1e30f, -1e30f, -1e30f};
  float l_r[4] = {0.f, 0.f, 0.f, 0.f};

  for (int kb = 0; kb < S; kb += 64) {
    // issue V-fragment loads early; consumed after softmax (latency hidden under QK+softmax)
    bf16x8 vf[2][4];
    #pragma unroll
    for (int ks = 0; ks < 2; ks++)
      #pragma unroll
      for (int nt = 0; nt < 4; nt++)
        vf[ks][nt] = *(const bf16x8*)(Vh + (size_t)(nt*16 + lrow) * S + kb + ks*32 + lgrp*8);

    // S = Q K^T  (scale folded into Q)
    f32x4 sacc[4];
    #pragma unroll
    for (int nt = 0; nt < 4; nt++) sacc[nt] = f32x4{0.f, 0.f, 0.f, 0.f};
    #pragma unroll
    for (int ks = 0; ks < 2; ks++) {
      #pragma unroll
      for (int nt = 0; nt < 4; nt++) {
        bf16x8 kf = *(const bf16x8*)(Kh + (size_t)(kb + nt*16 + lrow) * 64 + ks*32 + lgrp*8);
        sacc[nt] = __builtin_amdgcn_mfma_f32_16x16x32_bf16(qf[ks], kf, sacc[nt], 0, 0, 0);
      }
    }

    // online softmax (row r = lgrp*4+i; key cols spread over 16 lanes)
    float pm[4];
    #pragma unroll
    for (int i = 0; i < 4; i++)
      pm[i] = fmaxf(fmaxf(sacc[0][i], sacc[1][i]), fmaxf(sacc[2][i], sacc[3][i]));
    #pragma unroll
    for (int off = 1; off < 16; off <<= 1)
      #pragma unroll
      for (int i = 0; i < 4; i++) pm[i] = fmaxf(pm[i], __shfl_xor(pm[i], off, 64));
    float corr[4], rsum[4];
    #pragma unroll
    for (int i = 0; i < 4; i++) {
      float mnew = fmaxf(m_r[i], pm[i]);
      corr[i] = __expf(m_r[i] - mnew);
      m_r[i] = mnew;
      rsum[i] = 0.f;
    }
    #pragma unroll
    for (int nt = 0; nt < 4; nt++) {
      #pragma unroll
      for (int i = 0; i < 4; i++) {
        float p = __expf(sacc[nt][i] - m_r[i]);
        rsum[i] += p;
        int row = lgrp*4 + i;
        union { __bf16 b; unsigned short u; } cvp; cvp.b = (__bf16)p;
        Pb[w][row][(nt*16 + lrow) ^ ((row & 7) << 3)] = cvp.u;
      }
    }
    #pragma unroll
    for (int off = 1; off < 16; off <<= 1)
      #pragma unroll
      for (int i = 0; i < 4; i++) rsum[i] += __shfl_xor(rsum[i], off, 64);
    #pragma unroll
    for (int i = 0; i < 4; i++) l_r[i] = l_r[i] * corr[i] + rsum[i];
    #pragma unroll
    for (int nt = 0; nt < 4; nt++)
      #pragma unroll
      for (int i = 0; i < 4; i++) oacc[nt][i] *= corr[i];

    // O += P V  (P from per-wave LDS — same-wave dep, compiler inserts lgkmcnt; no barrier)
    #pragma unroll
    for (int ks = 0; ks < 2; ks++) {
      bf16x8 pf = *(const bf16x8*)(&Pb[w][lrow][(ks*32 + lgrp*8) ^ ((lrow & 7) << 3)]);
      #pragma unroll
      for (int nt = 0; nt < 4; nt++)
        oacc[nt] = __builtin_amdgcn_mfma_f32_16x16x32_bf16(pf, vf[ks][nt], oacc[nt], 0, 0, 0);
    }
  }

  // epilogue: write [B,S,H*64] bf16
  int b = bh >> 4, h = bh & 15;
  #pragma unroll
  for (int nt = 0; nt < 4; nt++) {
    int dd = nt*16 + lrow;
    #pragma unroll
    for (int i = 0; i < 4; i++) {
      int s = qbase + w*16 + lgrp*4 + i;
      float ov = oacc[nt][i] / l_r[i];
      O[((size_t)(b*2048 + s)) * 1024 + h*64 + dd] = f2bf(ov);
    }
  }
}

// ---------- launcher ----------
extern "C" void kernel_launch(void* const* d_in, const int* in_sizes, int n_in,
                              void* d_out, int out_size, void* d_ws, size_t ws_size,
                              hipStream_t stream)
{
  const float* x     = (const float*)d_in[0];
  const float* dwq_w = (const float*)d_in[1];
  const float* dwq_b = (const float*)d_in[2];
  const float* dwk_w = (const float*)d_in[3];
  const float* dwk_b = (const float*)d_in[4];
  const float* dwv_w = (const float*)d_in[5];
  const float* dwv_b = (const float*)d_in[6];
  const float* wq    = (const float*)d_in[7];
  const float* bq    = (const float*)d_in[8];
  const float* wk    = (const float*)d_in[9];
  const float* bk    = (const float*)d_in[10];
  const float* wv    = (const float*)d_in[11];
  const float* bv    = (const float*)d_in[12];
  const float* wo    = (const float*)d_in[13];
  const float* bo    = (const float*)d_in[14];
  float* out = (float*)d_out;

  char* ws = (char*)d_ws;
  const size_t MB = 1024 * 1024;
  unsigned short* cq  = (unsigned short*)(ws + 0);        // 8MB (reused as attn_out)
  unsigned short* ck  = (unsigned short*)(ws + 8*MB);     // 8MB (reused as vt)
  unsigned short* cv  = (unsigned short*)(ws + 16*MB);
  unsigned short* qd  = (unsigned short*)(ws + 24*MB);    // [B,H,S,64] bf16
  unsigned short* kd  = (unsigned short*)(ws + 32*MB);
  unsigned short* vd  = (unsigned short*)(ws + 40*MB);
  unsigned short* wqb = (unsigned short*)(ws + 48*MB);
  unsigned short* wkb = (unsigned short*)(ws + 50*MB);
  unsigned short* wvb = (unsigned short*)(ws + 52*MB);
  unsigned short* wob = (unsigned short*)(ws + 54*MB);
  unsigned short* attn_out = cq;                          // cq dead after gemm_qkv
  unsigned short* vt       = ck;                          // ck dead after gemm_qkv

  cvt_w_kernel<<<dim3(1024, 4), 256, 0, stream>>>(wq, wk, wv, wo, wqb, wkb, wvb, wob);
  conv3_kernel<<<16384, 256, 0, stream>>>(x, dwq_w, dwq_b, dwk_w, dwk_b, dwv_w, dwv_b, cq, ck, cv);
  gemm_qkv_kernel<<<dim3(8, 32, 3), 256, 0, stream>>>(cq, ck, cv, wqb, wkb, wvb, bq, bk, bv, qd, kd, vd);
  vtrans_kernel<<<dim3(32, 32), 256, 0, stream>>>(vd, vt);
  attn_kernel<<<512, 512, 0, stream>>>(qd, kd, vt, attn_out);
  gemm_out_kernel<<<dim3(8, 32), 256, 0, stream>>>(attn_out, wob, bo, out);
}

// Round 3
// 196.110 us; speedup vs baseline: 1.6088x; 1.6088x over previous
//
#include <hip/hip_runtime.h>

// ---------- types ----------
typedef __bf16 bf16x8 __attribute__((ext_vector_type(8)));
typedef float f32x4 __attribute__((ext_vector_type(4)));
typedef unsigned short u16x8 __attribute__((ext_vector_type(8)));

__device__ __forceinline__ unsigned short f2bf(float f) {
  union { float f; unsigned int u; } v; v.f = f;
  unsigned int r = v.u + 0x7FFFu + ((v.u >> 16) & 1u);
  return (unsigned short)(r >> 16);
}

// global -> LDS direct copy, 16B per lane; lds dst is wave-uniform base (+lane*16 by HW)
__device__ __forceinline__ void gload_lds16(const void* g, void* l) {
  __builtin_amdgcn_global_load_lds(
      (const __attribute__((address_space(1))) void*)g,
      (__attribute__((address_space(3))) void*)l, 16, 0, 0);
}

// ---------- conv: depthwise k=3 pad=1, three paths, bf16 out ----------
__global__ __launch_bounds__(256)
void conv3_kernel(const float* __restrict__ x,
                  const float* __restrict__ wq, const float* __restrict__ bq,
                  const float* __restrict__ wk, const float* __restrict__ bk,
                  const float* __restrict__ wv, const float* __restrict__ bv,
                  unsigned short* __restrict__ cq, unsigned short* __restrict__ ck,
                  unsigned short* __restrict__ cv)
{
  int idx = blockIdx.x * 256 + threadIdx.x;   // over B*S*D = 4194304
  int d = idx & 1023;
  int t = idx >> 10;          // b*2048+s
  int s = t & 2047;
  float xc = x[idx];
  float xm = (s > 0)    ? x[idx - 1024] : 0.0f;
  float xp = (s < 2047) ? x[idx + 1024] : 0.0f;
  cq[idx] = f2bf(xm * wq[d*3+0] + xc * wq[d*3+1] + xp * wq[d*3+2] + bq[d]);
  ck[idx] = f2bf(xm * wk[d*3+0] + xc * wk[d*3+1] + xp * wk[d*3+2] + bk[d]);
  cv[idx] = f2bf(xm * wv[d*3+0] + xc * wv[d*3+1] + xp * wv[d*3+2] + bv[d]);
}

// ---------- weight fp32 -> bf16 ----------
__global__ __launch_bounds__(256)
void cvt_w_kernel(const float* __restrict__ w0, const float* __restrict__ w1,
                  const float* __restrict__ w2, const float* __restrict__ w3,
                  unsigned short* __restrict__ o0, unsigned short* __restrict__ o1,
                  unsigned short* __restrict__ o2, unsigned short* __restrict__ o3)
{
  const float* src; unsigned short* dst;
  switch (blockIdx.y) {
    case 0: src = w0; dst = o0; break;
    case 1: src = w1; dst = o1; break;
    case 2: src = w2; dst = o2; break;
    default: src = w3; dst = o3; break;
  }
  int i = blockIdx.x * 1024 + threadIdx.x * 4;   // 1M elements per matrix
  float4 v = *(const float4*)(src + i);
  dst[i+0] = f2bf(v.x); dst[i+1] = f2bf(v.y);
  dst[i+2] = f2bf(v.z); dst[i+3] = f2bf(v.w);
}

// ---------- GEMM core: C[128x128] += A[bm..][K] * W[bn..][K]^T, K=1024, BK=32 ----------
__device__ __forceinline__ void gemm_tile_core(
    const unsigned short* __restrict__ A, const unsigned short* __restrict__ W,
    int bm, int bn, unsigned short* lA, unsigned short* lB, f32x4 acc[4][4])
{
  const int K = 1024;
  const int tid  = threadIdx.x;
  const int lane = tid & 63;
  const int w    = tid >> 6;            // wave 0..3
  const int lrow = lane & 15;
  const int lko  = (lane >> 4) * 8;     // k-offset within 32
  const int wm   = (w >> 1) * 64;
  const int wn   = (w & 1) * 64;

  #pragma unroll
  for (int i = 0; i < 4; i++)
    #pragma unroll
    for (int j = 0; j < 4; j++)
      acc[i][j] = f32x4{0.f, 0.f, 0.f, 0.f};

  for (int k0 = 0; k0 < K; k0 += 32) {
    // stage A and B tiles: 128x32 bf16 = 8KB each = 512 x 16B chunks; 4 chunks/row
    #pragma unroll
    for (int i = 0; i < 2; i++) {
      int ci  = (i * 4 + w) * 64 + lane;
      int row = ci >> 2;
      int kc  = (ci & 3) * 8;
      gload_lds16(A + (size_t)(bm + row) * K + (k0 + kc), lA + (size_t)(i*4 + w) * 512);
      gload_lds16(W + (size_t)(bn + row) * K + (k0 + kc), lB + (size_t)(i*4 + w) * 512);
    }
    __syncthreads();   // compiler drains vmcnt before barrier

    bf16x8 af[4], bfr[4];
    #pragma unroll
    for (int mt = 0; mt < 4; mt++)
      af[mt] = *(const bf16x8*)(lA + (wm + mt*16 + lrow) * 32 + lko);
    #pragma unroll
    for (int nt = 0; nt < 4; nt++)
      bfr[nt] = *(const bf16x8*)(lB + (wn + nt*16 + lrow) * 32 + lko);
    #pragma unroll
    for (int mt = 0; mt < 4; mt++)
      #pragma unroll
      for (int nt = 0; nt < 4; nt++)
        acc[mt][nt] = __builtin_amdgcn_mfma_f32_16x16x32_bf16(af[mt], bfr[nt], acc[mt][nt], 0, 0, 0);
    __syncthreads();
  }
}

// ---------- q/k/v projections, epilogue permutes to [B,H,S,64] bf16 ----------
__global__ __launch_bounds__(256)
void gemm_qkv_kernel(const unsigned short* __restrict__ cq, const unsigned short* __restrict__ ck,
                     const unsigned short* __restrict__ cv,
                     const unsigned short* __restrict__ wqb, const unsigned short* __restrict__ wkb,
                     const unsigned short* __restrict__ wvb,
                     const float* __restrict__ bq, const float* __restrict__ bk,
                     const float* __restrict__ bv,
                     unsigned short* __restrict__ qo, unsigned short* __restrict__ ko,
                     unsigned short* __restrict__ vo)
{
  __shared__ alignas(16) unsigned short lA[128 * 32];
  __shared__ alignas(16) unsigned short lB[128 * 32];
  int z = blockIdx.z;
  const unsigned short* A = (z == 0) ? cq : ((z == 1) ? ck : cv);
  const unsigned short* W = (z == 0) ? wqb : ((z == 1) ? wkb : wvb);
  const float* bias       = (z == 0) ? bq : ((z == 1) ? bk : bv);
  unsigned short* O       = (z == 0) ? qo : ((z == 1) ? ko : vo);
  float scale             = (z == 0) ? 0.125f : 1.0f;   // fold 1/sqrt(64) into Q (exact)

  int bm = blockIdx.y * 128, bn = blockIdx.x * 128;
  f32x4 acc[4][4];
  gemm_tile_core(A, W, bm, bn, lA, lB, acc);

  const int tid = threadIdx.x, lane = tid & 63, w = tid >> 6;
  const int lrow = lane & 15, lgrp = lane >> 4;
  const int wm = (w >> 1) * 64, wn = (w & 1) * 64;
  #pragma unroll
  for (int mt = 0; mt < 4; mt++) {
    #pragma unroll
    for (int nt = 0; nt < 4; nt++) {
      int gn = bn + wn + nt*16 + lrow;
      float bb = bias[gn];
      int h = gn >> 6, dk = gn & 63;
      #pragma unroll
      for (int i = 0; i < 4; i++) {
        int gm = bm + wm + mt*16 + lgrp*4 + i;     // b*2048+s
        int b = gm >> 11, s = gm & 2047;
        float val = (acc[mt][nt][i] + bb) * scale;
        O[((size_t)(b*16 + h) * 2048 + s) * 64 + dk] = f2bf(val);
      }
    }
  }
}

// ---------- final projection: f32 out ----------
__global__ __launch_bounds__(256)
void gemm_out_kernel(const unsigned short* __restrict__ A, const unsigned short* __restrict__ W,
                     const float* __restrict__ bias, float* __restrict__ Out)
{
  __shared__ alignas(16) unsigned short lA[128 * 32];
  __shared__ alignas(16) unsigned short lB[128 * 32];
  int bm = blockIdx.y * 128, bn = blockIdx.x * 128;
  f32x4 acc[4][4];
  gemm_tile_core(A, W, bm, bn, lA, lB, acc);

  const int tid = threadIdx.x, lane = tid & 63, w = tid >> 6;
  const int lrow = lane & 15, lgrp = lane >> 4;
  const int wm = (w >> 1) * 64, wn = (w & 1) * 64;
  #pragma unroll
  for (int mt = 0; mt < 4; mt++) {
    #pragma unroll
    for (int nt = 0; nt < 4; nt++) {
      int gn = bn + wn + nt*16 + lrow;
      float bb = bias[gn];
      #pragma unroll
      for (int i = 0; i < 4; i++) {
        int gm = bm + wm + mt*16 + lgrp*4 + i;
        Out[(size_t)gm * 1024 + gn] = acc[mt][nt][i] + bb;
      }
    }
  }
}

// ---------- V transpose to tile-blocked: [B,H,S,64] -> [bh][S/64][64d][64k] ----------
__global__ __launch_bounds__(256)
void vtrans_kernel(const unsigned short* __restrict__ V, unsigned short* __restrict__ Vtb)
{
  __shared__ alignas(16) unsigned short T[64][72];   // +8 pad: transpose bank spread
  int bh = blockIdx.y, sb6 = blockIdx.x;             // tile index along S
  int t = threadIdx.x;
  {
    int s_l = t >> 2, d0 = (t & 3) * 16;
    const unsigned short* src = V + ((size_t)bh * 2048 + sb6 * 64 + s_l) * 64 + d0;
    u16x8 a = *(const u16x8*)src;
    u16x8 b = *(const u16x8*)(src + 8);
    *(u16x8*)&T[s_l][d0]     = a;
    *(u16x8*)&T[s_l][d0 + 8] = b;
  }
  __syncthreads();
  {
    int d_l = t >> 2, s0 = (t & 3) * 16;
    u16x8 o0, o1;
    #pragma unroll
    for (int j = 0; j < 8; j++) { o0[j] = T[s0 + j][d_l]; o1[j] = T[s0 + 8 + j][d_l]; }
    unsigned short* dst = Vtb + (((size_t)bh * 32 + sb6) * 64 + d_l) * 64 + s0;
    *(u16x8*)dst       = o0;
    *(u16x8*)(dst + 8) = o1;
  }
}

// ---------- flash attention ----------
// 4 waves x 32 q-rows = 128 q-rows/block; 512 blocks (2/CU).
// K,V tiles (64 keys) staged in LDS, double-buffered, via global_load_lds with
// PRE-SWIZZLED SOURCE (linear LDS dest): chunk c of row r holds logical chunk c^(r&7).
// One barrier per KV-tile. P goes through per-wave swizzled LDS (no barrier needed).
__global__ __launch_bounds__(256, 2)
void attn_kernel(const unsigned short* __restrict__ Q, const unsigned short* __restrict__ K,
                 const unsigned short* __restrict__ Vtb, unsigned short* __restrict__ O)
{
  const int S = 2048, NT = 32;
  // XCD-aware decode: xcd = n&7 -> bh group of 4 (K/V working set 2MB/XCD-L2)
  int n = blockIdx.x;
  int xcd = n & 7, r = n >> 3;
  int bh = (xcd << 2) | (r & 3);
  int qbase = (r >> 2) * 128;

  const int tid = threadIdx.x, lane = tid & 63, w = tid >> 6;   // 4 waves
  const int lrow = lane & 15, lgrp = lane >> 4;
  const unsigned short* Qh = Q   + (size_t)bh * S * 64;
  const unsigned short* Kh = K   + (size_t)bh * S * 64;
  const unsigned short* Vh = Vtb + (size_t)bh * 32 * 4096;   // [tile][64d][64k]

  __shared__ alignas(16) unsigned short Kb[2][4096];
  __shared__ alignas(16) unsigned short Vb[2][4096];
  __shared__ alignas(16) unsigned short Pb[4][32 * 64];

  // Q fragments: 32 rows per wave (2 x 16-row tiles), k-split in 2
  bf16x8 qf[2][2];
  #pragma unroll
  for (int mt = 0; mt < 2; mt++)
    #pragma unroll
    for (int ks = 0; ks < 2; ks++)
      qf[mt][ks] = *(const bf16x8*)(Qh + (size_t)(qbase + w*32 + mt*16 + lrow) * 64 + ks*32 + lgrp*8);

  f32x4 oacc[2][4];
  float m_r[2][4], l_r[2][4];
  #pragma unroll
  for (int mt = 0; mt < 2; mt++)
    #pragma unroll
    for (int i = 0; i < 4; i++) {
      oacc[mt][i] = f32x4{0.f, 0.f, 0.f, 0.f};
      if (i < 4) { m_r[mt][i] = -1e30f; l_r[mt][i] = 0.f; }
    }

  // staging lambda: tile t -> buffer buf. 8KB per matrix = 512 chunks; 256 thr -> 2 each.
  // slot = c*256 + tid; row = slot>>3; src chunk = (slot&7) ^ (row&7)  (involution)
  auto STAGE = [&](int buf, int t) {
    const unsigned short* gK = Kh + (size_t)t * 4096;
    const unsigned short* gV = Vh + (size_t)t * 4096;
    #pragma unroll
    for (int c = 0; c < 2; c++) {
      int slot_base = c * 256 + w * 64;          // wave-uniform
      int slot = slot_base + lane;
      int row = slot >> 3;
      int srcoff = (row << 6) + (((slot & 7) ^ (row & 7)) << 3);
      gload_lds16(gK + srcoff, &Kb[buf][slot_base * 8]);
      gload_lds16(gV + srcoff, &Vb[buf][slot_base * 8]);
    }
  };

  STAGE(0, 0);
  __syncthreads();
  int cur = 0;

  for (int t = 0; t < NT; t++) {
    if (t + 1 < NT) STAGE(cur ^ 1, t + 1);

    // ---- S = Q K^T (scale folded into Q) ----
    f32x4 sacc[2][4];
    #pragma unroll
    for (int mt = 0; mt < 2; mt++)
      #pragma unroll
      for (int nt = 0; nt < 4; nt++) sacc[mt][nt] = f32x4{0.f, 0.f, 0.f, 0.f};
    #pragma unroll
    for (int ks = 0; ks < 2; ks++) {
      bf16x8 kf[4];
      #pragma unroll
      for (int nt = 0; nt < 4; nt++) {
        int rr = nt*16 + lrow;
        kf[nt] = *(const bf16x8*)(&Kb[cur][(rr << 6) + ((((ks << 2) + lgrp) ^ (rr & 7)) << 3)]);
      }
      #pragma unroll
      for (int mt = 0; mt < 2; mt++)
        #pragma unroll
        for (int nt = 0; nt < 4; nt++)
          sacc[mt][nt] = __builtin_amdgcn_mfma_f32_16x16x32_bf16(qf[mt][ks], kf[nt], sacc[mt][nt], 0, 0, 0);
    }

    // ---- online softmax; P -> per-wave swizzled LDS ----
    #pragma unroll
    for (int mt = 0; mt < 2; mt++) {
      float pm[4], corr[4], rsum[4];
      #pragma unroll
      for (int i = 0; i < 4; i++)
        pm[i] = fmaxf(fmaxf(sacc[mt][0][i], sacc[mt][1][i]), fmaxf(sacc[mt][2][i], sacc[mt][3][i]));
      #pragma unroll
      for (int off = 1; off < 16; off <<= 1)
        #pragma unroll
        for (int i = 0; i < 4; i++) pm[i] = fmaxf(pm[i], __shfl_xor(pm[i], off, 64));
      #pragma unroll
      for (int i = 0; i < 4; i++) {
        float mnew = fmaxf(m_r[mt][i], pm[i]);
        corr[i] = __expf(m_r[mt][i] - mnew);
        m_r[mt][i] = mnew;
        rsum[i] = 0.f;
      }
      #pragma unroll
      for (int nt = 0; nt < 4; nt++) {
        #pragma unroll
        for (int i = 0; i < 4; i++) {
          float p = __expf(sacc[mt][nt][i] - m_r[mt][i]);
          rsum[i] += p;
          int row_l = mt*16 + lgrp*4 + i;
          union { __bf16 b; unsigned short u; } cvp; cvp.b = (__bf16)p;
          Pb[w][(row_l << 6) + ((nt*16 + lrow) ^ ((row_l & 7) << 3))] = cvp.u;
        }
      }
      #pragma unroll
      for (int off = 1; off < 16; off <<= 1)
        #pragma unroll
        for (int i = 0; i < 4; i++) rsum[i] += __shfl_xor(rsum[i], off, 64);
      #pragma unroll
      for (int i = 0; i < 4; i++) l_r[mt][i] = l_r[mt][i] * corr[i] + rsum[i];
      #pragma unroll
      for (int nt = 0; nt < 4; nt++)
        #pragma unroll
        for (int i = 0; i < 4; i++) oacc[mt][nt][i] *= corr[i];
    }

    // ---- O += P V (P same-wave LDS; V from swizzled tile) ----
    #pragma unroll
    for (int ks = 0; ks < 2; ks++) {
      bf16x8 pf[2], vf[4];
      #pragma unroll
      for (int mt = 0; mt < 2; mt++) {
        int row_l = mt*16 + lrow;
        pf[mt] = *(const bf16x8*)(&Pb[w][(row_l << 6) + (((ks*4 + lgrp) ^ (lrow & 7)) << 3)]);
      }
      #pragma unroll
      for (int nt = 0; nt < 4; nt++) {
        int rr = nt*16 + lrow;
        vf[nt] = *(const bf16x8*)(&Vb[cur][(rr << 6) + ((((ks << 2) + lgrp) ^ (rr & 7)) << 3)]);
      }
      #pragma unroll
      for (int mt = 0; mt < 2; mt++)
        #pragma unroll
        for (int nt = 0; nt < 4; nt++)
          oacc[mt][nt] = __builtin_amdgcn_mfma_f32_16x16x32_bf16(pf[mt], vf[nt], oacc[mt][nt], 0, 0, 0);
    }

    __syncthreads();    // next tile staged; cur buffer free for overwrite
    cur ^= 1;
  }

  // epilogue: write [B,S,H*64] bf16
  int b = bh >> 4, h = bh & 15;
  #pragma unroll
  for (int mt = 0; mt < 2; mt++) {
    #pragma unroll
    for (int nt = 0; nt < 4; nt++) {
      int dd = nt*16 + lrow;
      #pragma unroll
      for (int i = 0; i < 4; i++) {
        int s = qbase + w*32 + mt*16 + lgrp*4 + i;
        float ov = oacc[mt][nt][i] / l_r[mt][i];
        O[((size_t)(b*2048 + s)) * 1024 + h*64 + dd] = f2bf(ov);
      }
    }
  }
}

// ---------- launcher ----------
extern "C" void kernel_launch(void* const* d_in, const int* in_sizes, int n_in,
                              void* d_out, int out_size, void* d_ws, size_t ws_size,
                              hipStream_t stream)
{
  const float* x     = (const float*)d_in[0];
  const float* dwq_w = (const float*)d_in[1];
  const float* dwq_b = (const float*)d_in[2];
  const float* dwk_w = (const float*)d_in[3];
  const float* dwk_b = (const float*)d_in[4];
  const float* dwv_w = (const float*)d_in[5];
  const float* dwv_b = (const float*)d_in[6];
  const float* wq    = (const float*)d_in[7];
  const float* bq    = (const float*)d_in[8];
  const float* wk    = (const float*)d_in[9];
  const float* bk    = (const float*)d_in[10];
  const float* wv    = (const float*)d_in[11];
  const float* bv    = (const float*)d_in[12];
  const float* wo    = (const float*)d_in[13];
  const float* bo    = (const float*)d_in[14];
  float* out = (float*)d_out;

  char* ws = (char*)d_ws;
  const size_t MB = 1024 * 1024;
  unsigned short* cq  = (unsigned short*)(ws + 0);        // 8MB (reused as attn_out)
  unsigned short* ck  = (unsigned short*)(ws + 8*MB);     // 8MB (reused as vtb)
  unsigned short* cv  = (unsigned short*)(ws + 16*MB);
  unsigned short* qd  = (unsigned short*)(ws + 24*MB);    // [B,H,S,64] bf16
  unsigned short* kd  = (unsigned short*)(ws + 32*MB);
  unsigned short* vd  = (unsigned short*)(ws + 40*MB);
  unsigned short* wqb = (unsigned short*)(ws + 48*MB);
  unsigned short* wkb = (unsigned short*)(ws + 50*MB);
  unsigned short* wvb = (unsigned short*)(ws + 52*MB);
  unsigned short* wob = (unsigned short*)(ws + 54*MB);
  unsigned short* attn_out = cq;                          // cq dead after gemm_qkv
  unsigned short* vtb      = ck;                          // ck dead after gemm_qkv

  cvt_w_kernel<<<dim3(1024, 4), 256, 0, stream>>>(wq, wk, wv, wo, wqb, wkb, wvb, wob);
  conv3_kernel<<<16384, 256, 0, stream>>>(x, dwq_w, dwq_b, dwk_w, dwk_b, dwv_w, dwv_b, cq, ck, cv);
  gemm_qkv_kernel<<<dim3(8, 32, 3), 256, 0, stream>>>(cq, ck, cv, wqb, wkb, wvb, bq, bk, bv, qd, kd, vd);
  vtrans_kernel<<<dim3(32, 32), 256, 0, stream>>>(vd, vtb);
  attn_kernel<<<512, 256, 0, stream>>>(qd, kd, vtb, attn_out);
  gemm_out_kernel<<<dim3(8, 32), 256, 0, stream>>>(attn_out, wob, bo, out);
}

// Round 4
// 184.239 us; speedup vs baseline: 1.7125x; 1.0644x over previous
//
#include <hip/hip_runtime.h>

// ---------- types ----------
typedef __bf16 bf16x8 __attribute__((ext_vector_type(8)));
typedef float f32x4 __attribute__((ext_vector_type(4)));
typedef unsigned short u16x8 __attribute__((ext_vector_type(8)));
typedef unsigned short u16x4 __attribute__((ext_vector_type(4)));

__device__ __forceinline__ unsigned short f2bf(float f) {
  union { float f; unsigned int u; } v; v.f = f;
  unsigned int r = v.u + 0x7FFFu + ((v.u >> 16) & 1u);
  return (unsigned short)(r >> 16);
}

// global -> LDS direct copy, 16B per lane; lds dst is wave-uniform base (+lane*16 by HW)
__device__ __forceinline__ void gload_lds16(const void* g, void* l) {
  __builtin_amdgcn_global_load_lds(
      (const __attribute__((address_space(1))) void*)g,
      (__attribute__((address_space(3))) void*)l, 16, 0, 0);
}

// ---------- conv: depthwise k=3 pad=1, 4 d's per thread, one (b,s) row per block ----------
__global__ __launch_bounds__(256)
void conv3_kernel(const float* __restrict__ x,
                  const float* __restrict__ wq, const float* __restrict__ bq,
                  const float* __restrict__ wk, const float* __restrict__ bk,
                  const float* __restrict__ wv, const float* __restrict__ bv,
                  unsigned short* __restrict__ cq, unsigned short* __restrict__ ck,
                  unsigned short* __restrict__ cv)
{
  int t = blockIdx.x;            // b*2048+s, 0..4095
  int s = t & 2047;
  int d0 = threadIdx.x * 4;
  int base = t * 1024 + d0;
  f32x4 xc = *(const f32x4*)(x + base);
  f32x4 xm = (s > 0)    ? *(const f32x4*)(x + base - 1024) : f32x4{0.f,0.f,0.f,0.f};
  f32x4 xp = (s < 2047) ? *(const f32x4*)(x + base + 1024) : f32x4{0.f,0.f,0.f,0.f};

  #pragma unroll
  for (int path = 0; path < 3; path++) {
    const float* wP = (path == 0) ? wq : ((path == 1) ? wk : wv);
    const float* bP = (path == 0) ? bq : ((path == 1) ? bk : bv);
    unsigned short* oP = (path == 0) ? cq : ((path == 1) ? ck : cv);
    f32x4 w0 = *(const f32x4*)(wP + d0*3);
    f32x4 w1 = *(const f32x4*)(wP + d0*3 + 4);
    f32x4 w2 = *(const f32x4*)(wP + d0*3 + 8);
    f32x4 b4 = *(const f32x4*)(bP + d0);
    u16x4 o;
    #pragma unroll
    for (int dd = 0; dd < 4; dd++) {
      // weight (dd, c) at flat j = dd*3+c
      float wa, wb, wc;
      int j0 = dd*3, j1 = dd*3+1, j2 = dd*3+2;
      wa = (j0 < 4) ? w0[j0] : ((j0 < 8) ? w1[j0-4] : w2[j0-8]);
      wb = (j1 < 4) ? w0[j1] : ((j1 < 8) ? w1[j1-4] : w2[j1-8]);
      wc = (j2 < 4) ? w0[j2] : ((j2 < 8) ? w1[j2-4] : w2[j2-8]);
      o[dd] = f2bf(xm[dd]*wa + xc[dd]*wb + xp[dd]*wc + b4[dd]);
    }
    *(u16x4*)(oP + base) = o;
  }
}

// ---------- weight fp32 -> bf16 ----------
__global__ __launch_bounds__(256)
void cvt_w_kernel(const float* __restrict__ w0, const float* __restrict__ w1,
                  const float* __restrict__ w2, const float* __restrict__ w3,
                  unsigned short* __restrict__ o0, unsigned short* __restrict__ o1,
                  unsigned short* __restrict__ o2, unsigned short* __restrict__ o3)
{
  const float* src; unsigned short* dst;
  switch (blockIdx.y) {
    case 0: src = w0; dst = o0; break;
    case 1: src = w1; dst = o1; break;
    case 2: src = w2; dst = o2; break;
    default: src = w3; dst = o3; break;
  }
  int i = blockIdx.x * 1024 + threadIdx.x * 4;   // 1M elements per matrix
  f32x4 v = *(const f32x4*)(src + i);
  u16x4 o;
  #pragma unroll
  for (int j = 0; j < 4; j++) o[j] = f2bf(v[j]);
  *(u16x4*)(dst + i) = o;
}

// ---------- GEMM core: C[128x128] += A[bm..][K] * W[bn..][K]^T, K=1024, BK=32 ----------
__device__ __forceinline__ void gemm_tile_core(
    const unsigned short* __restrict__ A, const unsigned short* __restrict__ W,
    int bm, int bn, unsigned short* lA, unsigned short* lB, f32x4 acc[4][4])
{
  const int K = 1024;
  const int tid  = threadIdx.x;
  const int lane = tid & 63;
  const int w    = tid >> 6;            // wave 0..3
  const int lrow = lane & 15;
  const int lko  = (lane >> 4) * 8;     // k-offset within 32
  const int wm   = (w >> 1) * 64;
  const int wn   = (w & 1) * 64;

  #pragma unroll
  for (int i = 0; i < 4; i++)
    #pragma unroll
    for (int j = 0; j < 4; j++)
      acc[i][j] = f32x4{0.f, 0.f, 0.f, 0.f};

  for (int k0 = 0; k0 < K; k0 += 32) {
    // stage A and B tiles: 128x32 bf16 = 8KB each = 512 x 16B chunks; 4 chunks/row
    #pragma unroll
    for (int i = 0; i < 2; i++) {
      int ci  = (i * 4 + w) * 64 + lane;
      int row = ci >> 2;
      int kc  = (ci & 3) * 8;
      gload_lds16(A + (size_t)(bm + row) * K + (k0 + kc), lA + (size_t)(i*4 + w) * 512);
      gload_lds16(W + (size_t)(bn + row) * K + (k0 + kc), lB + (size_t)(i*4 + w) * 512);
    }
    __syncthreads();   // compiler drains vmcnt before barrier

    bf16x8 af[4], bfr[4];
    #pragma unroll
    for (int mt = 0; mt < 4; mt++)
      af[mt] = *(const bf16x8*)(lA + (wm + mt*16 + lrow) * 32 + lko);
    #pragma unroll
    for (int nt = 0; nt < 4; nt++)
      bfr[nt] = *(const bf16x8*)(lB + (wn + nt*16 + lrow) * 32 + lko);
    #pragma unroll
    for (int mt = 0; mt < 4; mt++)
      #pragma unroll
      for (int nt = 0; nt < 4; nt++)
        acc[mt][nt] = __builtin_amdgcn_mfma_f32_16x16x32_bf16(af[mt], bfr[nt], acc[mt][nt], 0, 0, 0);
    __syncthreads();
  }
}

// ---------- q/k/v projections; q/k -> [B,H,S,64]; v -> tile-blocked [bh][S/64][64d][64k] ----------
__global__ __launch_bounds__(256)
void gemm_qkv_kernel(const unsigned short* __restrict__ cq, const unsigned short* __restrict__ ck,
                     const unsigned short* __restrict__ cv,
                     const unsigned short* __restrict__ wqb, const unsigned short* __restrict__ wkb,
                     const unsigned short* __restrict__ wvb,
                     const float* __restrict__ bq, const float* __restrict__ bk,
                     const float* __restrict__ bv,
                     unsigned short* __restrict__ qo, unsigned short* __restrict__ ko,
                     unsigned short* __restrict__ vtb)
{
  __shared__ alignas(16) unsigned short lA[128 * 32];
  __shared__ alignas(16) unsigned short lB[128 * 32];
  int z = blockIdx.z;
  const unsigned short* A = (z == 0) ? cq : ((z == 1) ? ck : cv);
  const unsigned short* W = (z == 0) ? wqb : ((z == 1) ? wkb : wvb);
  const float* bias       = (z == 0) ? bq : ((z == 1) ? bk : bv);
  float scale             = (z == 0) ? 0.125f : 1.0f;   // fold 1/sqrt(64) into Q (exact)

  int bm = blockIdx.y * 128, bn = blockIdx.x * 128;
  f32x4 acc[4][4];
  gemm_tile_core(A, W, bm, bn, lA, lB, acc);

  const int tid = threadIdx.x, lane = tid & 63, w = tid >> 6;
  const int lrow = lane & 15, lgrp = lane >> 4;
  const int wm = (w >> 1) * 64, wn = (w & 1) * 64;

  if (z == 2) {
    // V: write transposed tile-blocked; rows i=0..3 are consecutive s -> innermost k dim
    #pragma unroll
    for (int mt = 0; mt < 4; mt++) {
      #pragma unroll
      for (int nt = 0; nt < 4; nt++) {
        int gn = bn + wn + nt*16 + lrow;
        float bb = bias[gn];
        int h = gn >> 6, dk = gn & 63;
        int gm0 = bm + wm + mt*16 + lgrp*4;
        int b = gm0 >> 11, s0 = gm0 & 2047;
        u16x4 pk;
        #pragma unroll
        for (int i = 0; i < 4; i++) pk[i] = f2bf(acc[mt][nt][i] + bb);
        unsigned short* dst = vtb +
            ((((size_t)(b*16 + h)) * 32 + (s0 >> 6)) * 64 + dk) * 64 + (s0 & 63);
        *(u16x4*)dst = pk;
      }
    }
  } else {
    unsigned short* O = (z == 0) ? qo : ko;
    #pragma unroll
    for (int mt = 0; mt < 4; mt++) {
      #pragma unroll
      for (int nt = 0; nt < 4; nt++) {
        int gn = bn + wn + nt*16 + lrow;
        float bb = bias[gn];
        int h = gn >> 6, dk = gn & 63;
        #pragma unroll
        for (int i = 0; i < 4; i++) {
          int gm = bm + wm + mt*16 + lgrp*4 + i;     // b*2048+s
          int b = gm >> 11, s = gm & 2047;
          float val = (acc[mt][nt][i] + bb) * scale;
          O[((size_t)(b*16 + h) * 2048 + s) * 64 + dk] = f2bf(val);
        }
      }
    }
  }
}

// ---------- final projection: f32 out ----------
__global__ __launch_bounds__(256)
void gemm_out_kernel(const unsigned short* __restrict__ A, const unsigned short* __restrict__ W,
                     const float* __restrict__ bias, float* __restrict__ Out)
{
  __shared__ alignas(16) unsigned short lA[128 * 32];
  __shared__ alignas(16) unsigned short lB[128 * 32];
  int bm = blockIdx.y * 128, bn = blockIdx.x * 128;
  f32x4 acc[4][4];
  gemm_tile_core(A, W, bm, bn, lA, lB, acc);

  const int tid = threadIdx.x, lane = tid & 63, w = tid >> 6;
  const int lrow = lane & 15, lgrp = lane >> 4;
  const int wm = (w >> 1) * 64, wn = (w & 1) * 64;
  #pragma unroll
  for (int mt = 0; mt < 4; mt++) {
    #pragma unroll
    for (int nt = 0; nt < 4; nt++) {
      int gn = bn + wn + nt*16 + lrow;
      float bb = bias[gn];
      #pragma unroll
      for (int i = 0; i < 4; i++) {
        int gm = bm + wm + mt*16 + lgrp*4 + i;
        Out[(size_t)gm * 1024 + gn] = acc[mt][nt][i] + bb;
      }
    }
  }
}

// ---------- flash attention ----------
// 4 waves x 16 q-rows = 64 q-rows/block; grid 1024 = 4 blocks/CU (40KB LDS each).
// K,V tiles staged in LDS double-buffered via global_load_lds with pre-swizzled source.
// Row-sum l computed by MFMA against all-ones B (replaces shuffle-reduce).
__global__ __launch_bounds__(256, 4)
void attn_kernel(const unsigned short* __restrict__ Q, const unsigned short* __restrict__ K,
                 const unsigned short* __restrict__ Vtb, unsigned short* __restrict__ O)
{
  const int S = 2048, NT = 32;
  // XCD-aware decode: xcd = n&7 -> bh group of 4 (K/V working set 2MB/XCD-L2)
  int n = blockIdx.x;
  int xcd = n & 7, r = n >> 3;          // r: 0..127
  int bh = (xcd << 2) | (r & 3);
  int qbase = (r >> 2) * 64;

  const int tid = threadIdx.x, lane = tid & 63, w = tid >> 6;   // 4 waves
  const int lrow = lane & 15, lgrp = lane >> 4;
  const unsigned short* Qh = Q   + (size_t)bh * S * 64;
  const unsigned short* Kh = K   + (size_t)bh * S * 64;
  const unsigned short* Vh = Vtb + (size_t)bh * 32 * 4096;   // [tile][64d][64k]

  __shared__ alignas(16) unsigned short Kb[2][4096];
  __shared__ alignas(16) unsigned short Vb[2][4096];
  __shared__ alignas(16) unsigned short Pb[4][16 * 64];

  // Q fragments: 16 rows per wave
  bf16x8 qf[2];
  #pragma unroll
  for (int ks = 0; ks < 2; ks++)
    qf[ks] = *(const bf16x8*)(Qh + (size_t)(qbase + w*16 + lrow) * 64 + ks*32 + lgrp*8);

  bf16x8 ones;
  {
    union { __bf16 b; unsigned short u; } one; one.u = 0x3F80;
    #pragma unroll
    for (int j = 0; j < 8; j++) ones[j] = one.b;
  }

  f32x4 oacc[4], lacc;
  float m_r[4];
  #pragma unroll
  for (int i = 0; i < 4; i++) { oacc[i] = f32x4{0.f,0.f,0.f,0.f}; m_r[i] = -1e30f; }
  lacc = f32x4{0.f,0.f,0.f,0.f};

  // staging: 8KB per matrix = 512 chunks; 256 thr -> 2 each.
  // LDS[row][c] = global[row][c ^ (row&7)]  (involution; linear LDS dest, swizzled source)
  auto STAGE = [&](int buf, int t) {
    const unsigned short* gK = Kh + (size_t)t * 4096;
    const unsigned short* gV = Vh + (size_t)t * 4096;
    #pragma unroll
    for (int c = 0; c < 2; c++) {
      int slot_base = c * 256 + w * 64;          // wave-uniform
      int slot = slot_base + lane;
      int row = slot >> 3;
      int srcoff = (row << 6) + (((slot & 7) ^ (row & 7)) << 3);
      gload_lds16(gK + srcoff, &Kb[buf][slot_base * 8]);
      gload_lds16(gV + srcoff, &Vb[buf][slot_base * 8]);
    }
  };

  STAGE(0, 0);
  __syncthreads();
  int cur = 0;

  for (int t = 0; t < NT; t++) {
    if (t + 1 < NT) STAGE(cur ^ 1, t + 1);

    // ---- S = Q K^T (scale folded into Q) ----
    f32x4 sacc[4];
    #pragma unroll
    for (int nt = 0; nt < 4; nt++) sacc[nt] = f32x4{0.f,0.f,0.f,0.f};
    #pragma unroll
    for (int ks = 0; ks < 2; ks++) {
      bf16x8 kf[4];
      #pragma unroll
      for (int nt = 0; nt < 4; nt++) {
        int rr = nt*16 + lrow;
        kf[nt] = *(const bf16x8*)(&Kb[cur][(rr << 6) + ((((ks << 2) + lgrp) ^ (rr & 7)) << 3)]);
      }
      #pragma unroll
      for (int nt = 0; nt < 4; nt++)
        sacc[nt] = __builtin_amdgcn_mfma_f32_16x16x32_bf16(qf[ks], kf[nt], sacc[nt], 0, 0, 0);
    }

    // ---- online softmax: max-reduce + P->LDS; sum done later by ones-MFMA ----
    float pm[4], corr[4];
    #pragma unroll
    for (int i = 0; i < 4; i++)
      pm[i] = fmaxf(fmaxf(sacc[0][i], sacc[1][i]), fmaxf(sacc[2][i], sacc[3][i]));
    #pragma unroll
    for (int off = 1; off < 16; off <<= 1)
      #pragma unroll
      for (int i = 0; i < 4; i++) pm[i] = fmaxf(pm[i], __shfl_xor(pm[i], off, 64));
    #pragma unroll
    for (int i = 0; i < 4; i++) {
      float mnew = fmaxf(m_r[i], pm[i]);
      corr[i] = __expf(m_r[i] - mnew);
      m_r[i] = mnew;
    }
    #pragma unroll
    for (int nt = 0; nt < 4; nt++) {
      #pragma unroll
      for (int i = 0; i < 4; i++) {
        float p = __expf(sacc[nt][i] - m_r[i]);
        int row_l = lgrp*4 + i;
        union { __bf16 b; unsigned short u; } cvp; cvp.b = (__bf16)p;
        Pb[w][(row_l << 6) + ((nt*16 + lrow) ^ ((row_l & 7) << 3))] = cvp.u;
      }
    }
    #pragma unroll
    for (int nt = 0; nt < 4; nt++)
      #pragma unroll
      for (int i = 0; i < 4; i++) oacc[nt][i] *= corr[i];
    #pragma unroll
    for (int i = 0; i < 4; i++) lacc[i] *= corr[i];

    // ---- O += P V; l += P @ ones (P same-wave LDS; V from swizzled tile) ----
    #pragma unroll
    for (int ks = 0; ks < 2; ks++) {
      bf16x8 pf = *(const bf16x8*)(&Pb[w][(lrow << 6) + (((ks*4 + lgrp) ^ (lrow & 7)) << 3)]);
      bf16x8 vf[4];
      #pragma unroll
      for (int nt = 0; nt < 4; nt++) {
        int rr = nt*16 + lrow;
        vf[nt] = *(const bf16x8*)(&Vb[cur][(rr << 6) + ((((ks << 2) + lgrp) ^ (rr & 7)) << 3)]);
      }
      #pragma unroll
      for (int nt = 0; nt < 4; nt++)
        oacc[nt] = __builtin_amdgcn_mfma_f32_16x16x32_bf16(pf, vf[nt], oacc[nt], 0, 0, 0);
      lacc = __builtin_amdgcn_mfma_f32_16x16x32_bf16(pf, ones, lacc, 0, 0, 0);
    }

    __syncthreads();    // next tile staged; cur buffer free for overwrite
    cur ^= 1;
  }

  // epilogue: write [B,S,H*64] bf16
  int b = bh >> 4, h = bh & 15;
  float rl[4];
  #pragma unroll
  for (int i = 0; i < 4; i++) rl[i] = 1.0f / lacc[i];
  #pragma unroll
  for (int nt = 0; nt < 4; nt++) {
    int dd = nt*16 + lrow;
    #pragma unroll
    for (int i = 0; i < 4; i++) {
      int s = qbase + w*16 + lgrp*4 + i;
      float ov = oacc[nt][i] * rl[i];
      O[((size_t)(b*2048 + s)) * 1024 + h*64 + dd] = f2bf(ov);
    }
  }
}

// ---------- launcher ----------
extern "C" void kernel_launch(void* const* d_in, const int* in_sizes, int n_in,
                              void* d_out, int out_size, void* d_ws, size_t ws_size,
                              hipStream_t stream)
{
  const float* x     = (const float*)d_in[0];
  const float* dwq_w = (const float*)d_in[1];
  const float* dwq_b = (const float*)d_in[2];
  const float* dwk_w = (const float*)d_in[3];
  const float* dwk_b = (const float*)d_in[4];
  const float* dwv_w = (const float*)d_in[5];
  const float* dwv_b = (const float*)d_in[6];
  const float* wq    = (const float*)d_in[7];
  const float* bq    = (const float*)d_in[8];
  const float* wk    = (const float*)d_in[9];
  const float* bk    = (const float*)d_in[10];
  const float* wv    = (const float*)d_in[11];
  const float* bv    = (const float*)d_in[12];
  const float* wo    = (const float*)d_in[13];
  const float* bo    = (const float*)d_in[14];
  float* out = (float*)d_out;

  char* ws = (char*)d_ws;
  const size_t MB = 1024 * 1024;
  unsigned short* cq  = (unsigned short*)(ws + 0);        // 8MB (reused as attn_out)
  unsigned short* ck  = (unsigned short*)(ws + 8*MB);     // 8MB (reused as vtb)
  unsigned short* cv  = (unsigned short*)(ws + 16*MB);
  unsigned short* qd  = (unsigned short*)(ws + 24*MB);    // [B,H,S,64] bf16
  unsigned short* kd  = (unsigned short*)(ws + 32*MB);
  unsigned short* wqb = (unsigned short*)(ws + 48*MB);
  unsigned short* wkb = (unsigned short*)(ws + 50*MB);
  unsigned short* wvb = (unsigned short*)(ws + 52*MB);
  unsigned short* wob = (unsigned short*)(ws + 54*MB);
  unsigned short* attn_out = cq;                          // cq dead after gemm_qkv
  unsigned short* vtb      = ck;                          // ck dead after gemm_qkv

  cvt_w_kernel<<<dim3(1024, 4), 256, 0, stream>>>(wq, wk, wv, wo, wqb, wkb, wvb, wob);
  conv3_kernel<<<4096, 256, 0, stream>>>(x, dwq_w, dwq_b, dwk_w, dwk_b, dwv_w, dwv_b, cq, ck, cv);
  gemm_qkv_kernel<<<dim3(8, 32, 3), 256, 0, stream>>>(cq, ck, cv, wqb, wkb, wvb, bq, bk, bv, qd, kd, vtb);
  attn_kernel<<<1024, 256, 0, stream>>>(qd, kd, vtb, attn_out);
  gemm_out_kernel<<<dim3(8, 32), 256, 0, stream>>>(attn_out, wob, bo, out);
}

// Round 5
// 180.215 us; speedup vs baseline: 1.7507x; 1.0223x over previous
//
#include <hip/hip_runtime.h>

// ---------- types ----------
typedef __bf16 bf16x8 __attribute__((ext_vector_type(8)));
typedef float f32x4 __attribute__((ext_vector_type(4)));
typedef unsigned short u16x8 __attribute__((ext_vector_type(8)));
typedef unsigned short u16x4 __attribute__((ext_vector_type(4)));

__device__ __forceinline__ unsigned short f2bf(float f) {
  union { float f; unsigned int u; } v; v.f = f;
  unsigned int r = v.u + 0x7FFFu + ((v.u >> 16) & 1u);
  return (unsigned short)(r >> 16);
}

// global -> LDS direct copy, 16B per lane; lds dst is wave-uniform base (+lane*16 by HW)
__device__ __forceinline__ void gload_lds16(const void* g, void* l) {
  __builtin_amdgcn_global_load_lds(
      (const __attribute__((address_space(1))) void*)g,
      (__attribute__((address_space(3))) void*)l, 16, 0, 0);
}

// ---------- conv: depthwise k=3 pad=1, 4 d's per thread, one (b,s) row per block ----------
__global__ __launch_bounds__(256)
void conv3_kernel(const float* __restrict__ x,
                  const float* __restrict__ wq, const float* __restrict__ bq,
                  const float* __restrict__ wk, const float* __restrict__ bk,
                  const float* __restrict__ wv, const float* __restrict__ bv,
                  unsigned short* __restrict__ cq, unsigned short* __restrict__ ck,
                  unsigned short* __restrict__ cv)
{
  int t = blockIdx.x;            // b*2048+s, 0..4095
  int s = t & 2047;
  int d0 = threadIdx.x * 4;
  int base = t * 1024 + d0;
  f32x4 xc = *(const f32x4*)(x + base);
  f32x4 xm = (s > 0)    ? *(const f32x4*)(x + base - 1024) : f32x4{0.f,0.f,0.f,0.f};
  f32x4 xp = (s < 2047) ? *(const f32x4*)(x + base + 1024) : f32x4{0.f,0.f,0.f,0.f};

  #pragma unroll
  for (int path = 0; path < 3; path++) {
    const float* wP = (path == 0) ? wq : ((path == 1) ? wk : wv);
    const float* bP = (path == 0) ? bq : ((path == 1) ? bk : bv);
    unsigned short* oP = (path == 0) ? cq : ((path == 1) ? ck : cv);
    f32x4 w0 = *(const f32x4*)(wP + d0*3);
    f32x4 w1 = *(const f32x4*)(wP + d0*3 + 4);
    f32x4 w2 = *(const f32x4*)(wP + d0*3 + 8);
    f32x4 b4 = *(const f32x4*)(bP + d0);
    u16x4 o;
    #pragma unroll
    for (int dd = 0; dd < 4; dd++) {
      float wa, wb, wc;
      int j0 = dd*3, j1 = dd*3+1, j2 = dd*3+2;
      wa = (j0 < 4) ? w0[j0] : ((j0 < 8) ? w1[j0-4] : w2[j0-8]);
      wb = (j1 < 4) ? w0[j1] : ((j1 < 8) ? w1[j1-4] : w2[j1-8]);
      wc = (j2 < 4) ? w0[j2] : ((j2 < 8) ? w1[j2-4] : w2[j2-8]);
      o[dd] = f2bf(xm[dd]*wa + xc[dd]*wb + xp[dd]*wc + b4[dd]);
    }
    *(u16x4*)(oP + base) = o;
  }
}

// ---------- weight fp32 -> bf16 ----------
__global__ __launch_bounds__(256)
void cvt_w_kernel(const float* __restrict__ w0, const float* __restrict__ w1,
                  const float* __restrict__ w2, const float* __restrict__ w3,
                  unsigned short* __restrict__ o0, unsigned short* __restrict__ o1,
                  unsigned short* __restrict__ o2, unsigned short* __restrict__ o3)
{
  const float* src; unsigned short* dst;
  switch (blockIdx.y) {
    case 0: src = w0; dst = o0; break;
    case 1: src = w1; dst = o1; break;
    case 2: src = w2; dst = o2; break;
    default: src = w3; dst = o3; break;
  }
  int i = blockIdx.x * 1024 + threadIdx.x * 4;   // 1M elements per matrix
  f32x4 v = *(const f32x4*)(src + i);
  u16x4 o;
  #pragma unroll
  for (int j = 0; j < 4; j++) o[j] = f2bf(v[j]);
  *(u16x4*)(dst + i) = o;
}

// ---------- GEMM core: C[128x128] += A[bm..][K] * W[bn..][K]^T, K=1024, BK=32 ----------
__device__ __forceinline__ void gemm_tile_core(
    const unsigned short* __restrict__ A, const unsigned short* __restrict__ W,
    int bm, int bn, unsigned short* lA, unsigned short* lB, f32x4 acc[4][4])
{
  const int K = 1024;
  const int tid  = threadIdx.x;
  const int lane = tid & 63;
  const int w    = tid >> 6;            // wave 0..3
  const int lrow = lane & 15;
  const int lko  = (lane >> 4) * 8;     // k-offset within 32
  const int wm   = (w >> 1) * 64;
  const int wn   = (w & 1) * 64;

  #pragma unroll
  for (int i = 0; i < 4; i++)
    #pragma unroll
    for (int j = 0; j < 4; j++)
      acc[i][j] = f32x4{0.f, 0.f, 0.f, 0.f};

  for (int k0 = 0; k0 < K; k0 += 32) {
    // stage A and B tiles: 128x32 bf16 = 8KB each = 512 x 16B chunks; 4 chunks/row
    #pragma unroll
    for (int i = 0; i < 2; i++) {
      int ci  = (i * 4 + w) * 64 + lane;
      int row = ci >> 2;
      int kc  = (ci & 3) * 8;
      gload_lds16(A + (size_t)(bm + row) * K + (k0 + kc), lA + (size_t)(i*4 + w) * 512);
      gload_lds16(W + (size_t)(bn + row) * K + (k0 + kc), lB + (size_t)(i*4 + w) * 512);
    }
    __syncthreads();   // compiler drains vmcnt before barrier

    bf16x8 af[4], bfr[4];
    #pragma unroll
    for (int mt = 0; mt < 4; mt++)
      af[mt] = *(const bf16x8*)(lA + (wm + mt*16 + lrow) * 32 + lko);
    #pragma unroll
    for (int nt = 0; nt < 4; nt++)
      bfr[nt] = *(const bf16x8*)(lB + (wn + nt*16 + lrow) * 32 + lko);
    #pragma unroll
    for (int mt = 0; mt < 4; mt++)
      #pragma unroll
      for (int nt = 0; nt < 4; nt++)
        acc[mt][nt] = __builtin_amdgcn_mfma_f32_16x16x32_bf16(af[mt], bfr[nt], acc[mt][nt], 0, 0, 0);
    __syncthreads();
  }
}

// ---------- q/k/v projections; q/k -> [B,H,S,64]; v -> tile-blocked [bh][S/64][64d][64k] ----------
__global__ __launch_bounds__(256)
void gemm_qkv_kernel(const unsigned short* __restrict__ cq, const unsigned short* __restrict__ ck,
                     const unsigned short* __restrict__ cv,
                     const unsigned short* __restrict__ wqb, const unsigned short* __restrict__ wkb,
                     const unsigned short* __restrict__ wvb,
                     const float* __restrict__ bq, const float* __restrict__ bk,
                     const float* __restrict__ bv,
                     unsigned short* __restrict__ qo, unsigned short* __restrict__ ko,
                     unsigned short* __restrict__ vtb)
{
  __shared__ alignas(16) unsigned short lA[128 * 32];
  __shared__ alignas(16) unsigned short lB[128 * 32];
  int z = blockIdx.z;
  const unsigned short* A = (z == 0) ? cq : ((z == 1) ? ck : cv);
  const unsigned short* W = (z == 0) ? wqb : ((z == 1) ? wkb : wvb);
  const float* bias       = (z == 0) ? bq : ((z == 1) ? bk : bv);
  float scale             = (z == 0) ? 0.125f : 1.0f;   // fold 1/sqrt(64) into Q (exact)

  int bm = blockIdx.y * 128, bn = blockIdx.x * 128;
  f32x4 acc[4][4];
  gemm_tile_core(A, W, bm, bn, lA, lB, acc);

  const int tid = threadIdx.x, lane = tid & 63, w = tid >> 6;
  const int lrow = lane & 15, lgrp = lane >> 4;
  const int wm = (w >> 1) * 64, wn = (w & 1) * 64;

  if (z == 2) {
    // V: write transposed tile-blocked; rows i=0..3 are consecutive s -> innermost k dim
    #pragma unroll
    for (int mt = 0; mt < 4; mt++) {
      #pragma unroll
      for (int nt = 0; nt < 4; nt++) {
        int gn = bn + wn + nt*16 + lrow;
        float bb = bias[gn];
        int h = gn >> 6, dk = gn & 63;
        int gm0 = bm + wm + mt*16 + lgrp*4;
        int b = gm0 >> 11, s0 = gm0 & 2047;
        u16x4 pk;
        #pragma unroll
        for (int i = 0; i < 4; i++) pk[i] = f2bf(acc[mt][nt][i] + bb);
        unsigned short* dst = vtb +
            ((((size_t)(b*16 + h)) * 32 + (s0 >> 6)) * 64 + dk) * 64 + (s0 & 63);
        *(u16x4*)dst = pk;
      }
    }
  } else {
    unsigned short* O = (z == 0) ? qo : ko;
    #pragma unroll
    for (int mt = 0; mt < 4; mt++) {
      #pragma unroll
      for (int nt = 0; nt < 4; nt++) {
        int gn = bn + wn + nt*16 + lrow;
        float bb = bias[gn];
        int h = gn >> 6, dk = gn & 63;
        #pragma unroll
        for (int i = 0; i < 4; i++) {
          int gm = bm + wm + mt*16 + lgrp*4 + i;     // b*2048+s
          int b = gm >> 11, s = gm & 2047;
          float val = (acc[mt][nt][i] + bb) * scale;
          O[((size_t)(b*16 + h) * 2048 + s) * 64 + dk] = f2bf(val);
        }
      }
    }
  }
}

// ---------- final projection: f32 out ----------
__global__ __launch_bounds__(256)
void gemm_out_kernel(const unsigned short* __restrict__ A, const unsigned short* __restrict__ W,
                     const float* __restrict__ bias, float* __restrict__ Out)
{
  __shared__ alignas(16) unsigned short lA[128 * 32];
  __shared__ alignas(16) unsigned short lB[128 * 32];
  int bm = blockIdx.y * 128, bn = blockIdx.x * 128;
  f32x4 acc[4][4];
  gemm_tile_core(A, W, bm, bn, lA, lB, acc);

  const int tid = threadIdx.x, lane = tid & 63, w = tid >> 6;
  const int lrow = lane & 15, lgrp = lane >> 4;
  const int wm = (w >> 1) * 64, wn = (w & 1) * 64;
  #pragma unroll
  for (int mt = 0; mt < 4; mt++) {
    #pragma unroll
    for (int nt = 0; nt < 4; nt++) {
      int gn = bn + wn + nt*16 + lrow;
      float bb = bias[gn];
      #pragma unroll
      for (int i = 0; i < 4; i++) {
        int gm = bm + wm + mt*16 + lgrp*4 + i;
        Out[(size_t)gm * 1024 + gn] = acc[mt][nt][i] + bb;
      }
    }
  }
}

// ---------- flash attention ----------
// 4 waves x 32 q-rows = 128 q-rows/block; grid 512 = 2 blocks/CU (48KB LDS).
// K/V fragments read ONCE per iter, reused for 2 q-subtiles (halves DS bytes/q-row).
// K,V staged via global_load_lds with pre-swizzled source; dbuf, one barrier/tile.
// defer-max (T13): skip rescale pass when max growth <= 8 (wave-uniform branch).
// Row-sum l via ones-MFMA.
__global__ __launch_bounds__(256, 2)
void attn_kernel(const unsigned short* __restrict__ Q, const unsigned short* __restrict__ K,
                 const unsigned short* __restrict__ Vtb, unsigned short* __restrict__ O)
{
  const int S = 2048, NT = 32;
  // XCD-aware decode: xcd = n&7 -> bh group of 4 (K/V working set 2MB/XCD-L2)
  int n = blockIdx.x;
  int xcd = n & 7, r = n >> 3;          // r: 0..63
  int bh = (xcd << 2) | (r & 3);
  int qbase = (r >> 2) * 128;

  const int tid = threadIdx.x, lane = tid & 63, w = tid >> 6;   // 4 waves
  const int lrow = lane & 15, lgrp = lane >> 4;
  const unsigned short* Qh = Q   + (size_t)bh * S * 64;
  const unsigned short* Kh = K   + (size_t)bh * S * 64;
  const unsigned short* Vh = Vtb + (size_t)bh * 32 * 4096;   // [tile][64d][64k]

  __shared__ alignas(16) unsigned short Kb[2][4096];
  __shared__ alignas(16) unsigned short Vb[2][4096];
  __shared__ alignas(16) unsigned short Pb[4][32 * 64];   // per-wave, 32 rows, swizzled

  // Q fragments: 32 rows per wave = 2 x 16-row subtiles
  bf16x8 qf[2][2];
  #pragma unroll
  for (int sub = 0; sub < 2; sub++)
    #pragma unroll
    for (int ks = 0; ks < 2; ks++)
      qf[sub][ks] = *(const bf16x8*)(Qh + (size_t)(qbase + w*32 + sub*16 + lrow) * 64 + ks*32 + lgrp*8);

  bf16x8 ones;
  {
    union { __bf16 b; unsigned short u; } one; one.u = 0x3F80;
    #pragma unroll
    for (int j = 0; j < 8; j++) ones[j] = one.b;
  }

  f32x4 oacc[2][4], lacc[2];
  float m_r[2][4];
  #pragma unroll
  for (int sub = 0; sub < 2; sub++) {
    #pragma unroll
    for (int i = 0; i < 4; i++) { oacc[sub][i] = f32x4{0.f,0.f,0.f,0.f}; m_r[sub][i] = -1e30f; }
    lacc[sub] = f32x4{0.f,0.f,0.f,0.f};
  }

  // staging: 8KB per matrix = 512 chunks; 256 thr -> 2 each.
  // LDS[row][c] = global[row][c ^ (row&7)]  (involution; linear LDS dest, swizzled source)
  auto STAGE = [&](int buf, int t) {
    const unsigned short* gK = Kh + (size_t)t * 4096;
    const unsigned short* gV = Vh + (size_t)t * 4096;
    #pragma unroll
    for (int c = 0; c < 2; c++) {
      int slot_base = c * 256 + w * 64;          // wave-uniform
      int slot = slot_base + lane;
      int row = slot >> 3;
      int srcoff = (row << 6) + (((slot & 7) ^ (row & 7)) << 3);
      gload_lds16(gK + srcoff, &Kb[buf][slot_base * 8]);
      gload_lds16(gV + srcoff, &Vb[buf][slot_base * 8]);
    }
  };

  STAGE(0, 0);
  __syncthreads();
  int cur = 0;

  for (int t = 0; t < NT; t++) {
    if (t + 1 < NT) STAGE(cur ^ 1, t + 1);

    // ---- S = Q K^T (scale folded into Q); K-frags read once, used by both subs ----
    f32x4 sacc[2][4];
    #pragma unroll
    for (int sub = 0; sub < 2; sub++)
      #pragma unroll
      for (int nt = 0; nt < 4; nt++) sacc[sub][nt] = f32x4{0.f,0.f,0.f,0.f};
    #pragma unroll
    for (int ks = 0; ks < 2; ks++) {
      bf16x8 kf[4];
      #pragma unroll
      for (int nt = 0; nt < 4; nt++) {
        int rr = nt*16 + lrow;
        kf[nt] = *(const bf16x8*)(&Kb[cur][(rr << 6) + ((((ks << 2) + lgrp) ^ (rr & 7)) << 3)]);
      }
      #pragma unroll
      for (int sub = 0; sub < 2; sub++)
        #pragma unroll
        for (int nt = 0; nt < 4; nt++)
          sacc[sub][nt] = __builtin_amdgcn_mfma_f32_16x16x32_bf16(qf[sub][ks], kf[nt], sacc[sub][nt], 0, 0, 0);
    }

    // ---- online softmax with defer-max ----
    float pm[2][4];
    #pragma unroll
    for (int sub = 0; sub < 2; sub++)
      #pragma unroll
      for (int i = 0; i < 4; i++)
        pm[sub][i] = fmaxf(fmaxf(sacc[sub][0][i], sacc[sub][1][i]),
                           fmaxf(sacc[sub][2][i], sacc[sub][3][i]));
    #pragma unroll
    for (int off = 1; off < 16; off <<= 1)
      #pragma unroll
      for (int sub = 0; sub < 2; sub++)
        #pragma unroll
        for (int i = 0; i < 4; i++)
          pm[sub][i] = fmaxf(pm[sub][i], __shfl_xor(pm[sub][i], off, 64));

    bool grow_ok = true;
    #pragma unroll
    for (int sub = 0; sub < 2; sub++)
      #pragma unroll
      for (int i = 0; i < 4; i++)
        grow_ok = grow_ok && (pm[sub][i] <= m_r[sub][i] + 8.0f);
    if (!__all(grow_ok)) {
      // full rescale pass (rows that didn't grow get corr = 1)
      #pragma unroll
      for (int sub = 0; sub < 2; sub++) {
        #pragma unroll
        for (int i = 0; i < 4; i++) {
          float mnew = fmaxf(m_r[sub][i], pm[sub][i]);
          float corr = __expf(m_r[sub][i] - mnew);
          m_r[sub][i] = mnew;
          #pragma unroll
          for (int nt = 0; nt < 4; nt++) oacc[sub][nt][i] *= corr;
          lacc[sub][i] *= corr;
        }
      }
    }

    // ---- P = exp(S - m) -> per-wave swizzled LDS ----
    #pragma unroll
    for (int sub = 0; sub < 2; sub++) {
      #pragma unroll
      for (int nt = 0; nt < 4; nt++) {
        #pragma unroll
        for (int i = 0; i < 4; i++) {
          float p = __expf(sacc[sub][nt][i] - m_r[sub][i]);
          int row_l = sub*16 + lgrp*4 + i;
          union { __bf16 b; unsigned short u; } cvp; cvp.b = (__bf16)p;
          Pb[w][(row_l << 6) + ((nt*16 + lrow) ^ ((row_l & 7) << 3))] = cvp.u;
        }
      }
    }

    // ---- O += P V; l += P @ ones (V-frags read once, reused for both subs) ----
    __builtin_amdgcn_s_setprio(1);
    #pragma unroll
    for (int ks = 0; ks < 2; ks++) {
      bf16x8 pf[2], vf[4];
      #pragma unroll
      for (int sub = 0; sub < 2; sub++) {
        int row_l = sub*16 + lrow;
        pf[sub] = *(const bf16x8*)(&Pb[w][(row_l << 6) + (((ks*4 + lgrp) ^ (row_l & 7)) << 3)]);
      }
      #pragma unroll
      for (int nt = 0; nt < 4; nt++) {
        int rr = nt*16 + lrow;
        vf[nt] = *(const bf16x8*)(&Vb[cur][(rr << 6) + ((((ks << 2) + lgrp) ^ (rr & 7)) << 3)]);
      }
      #pragma unroll
      for (int sub = 0; sub < 2; sub++) {
        #pragma unroll
        for (int nt = 0; nt < 4; nt++)
          oacc[sub][nt] = __builtin_amdgcn_mfma_f32_16x16x32_bf16(pf[sub], vf[nt], oacc[sub][nt], 0, 0, 0);
        lacc[sub] = __builtin_amdgcn_mfma_f32_16x16x32_bf16(pf[sub], ones, lacc[sub], 0, 0, 0);
      }
    }
    __builtin_amdgcn_s_setprio(0);

    __syncthreads();    // next tile staged; cur buffer free for overwrite
    cur ^= 1;
  }

  // epilogue: write [B,S,H*64] bf16
  int b = bh >> 4, h = bh & 15;
  #pragma unroll
  for (int sub = 0; sub < 2; sub++) {
    float rl[4];
    #pragma unroll
    for (int i = 0; i < 4; i++) rl[i] = 1.0f / lacc[sub][i];
    #pragma unroll
    for (int nt = 0; nt < 4; nt++) {
      int dd = nt*16 + lrow;
      #pragma unroll
      for (int i = 0; i < 4; i++) {
        int s = qbase + w*32 + sub*16 + lgrp*4 + i;
        float ov = oacc[sub][nt][i] * rl[i];
        O[((size_t)(b*2048 + s)) * 1024 + h*64 + dd] = f2bf(ov);
      }
    }
  }
}

// ---------- launcher ----------
extern "C" void kernel_launch(void* const* d_in, const int* in_sizes, int n_in,
                              void* d_out, int out_size, void* d_ws, size_t ws_size,
                              hipStream_t stream)
{
  const float* x     = (const float*)d_in[0];
  const float* dwq_w = (const float*)d_in[1];
  const float* dwq_b = (const float*)d_in[2];
  const float* dwk_w = (const float*)d_in[3];
  const float* dwk_b = (const float*)d_in[4];
  const float* dwv_w = (const float*)d_in[5];
  const float* dwv_b = (const float*)d_in[6];
  const float* wq    = (const float*)d_in[7];
  const float* bq    = (const float*)d_in[8];
  const float* wk    = (const float*)d_in[9];
  const float* bk    = (const float*)d_in[10];
  const float* wv    = (const float*)d_in[11];
  const float* bv    = (const float*)d_in[12];
  const float* wo    = (const float*)d_in[13];
  const float* bo    = (const float*)d_in[14];
  float* out = (float*)d_out;

  char* ws = (char*)d_ws;
  const size_t MB = 1024 * 1024;
  unsigned short* cq  = (unsigned short*)(ws + 0);        // 8MB (reused as attn_out)
  unsigned short* ck  = (unsigned short*)(ws + 8*MB);     // 8MB (reused as vtb)
  unsigned short* cv  = (unsigned short*)(ws + 16*MB);
  unsigned short* qd  = (unsigned short*)(ws + 24*MB);    // [B,H,S,64] bf16
  unsigned short* kd  = (unsigned short*)(ws + 32*MB);
  unsigned short* wqb = (unsigned short*)(ws + 48*MB);
  unsigned short* wkb = (unsigned short*)(ws + 50*MB);
  unsigned short* wvb = (unsigned short*)(ws + 52*MB);
  unsigned short* wob = (unsigned short*)(ws + 54*MB);
  unsigned short* attn_out = cq;                          // cq dead after gemm_qkv
  unsigned short* vtb      = ck;                          // ck dead after gemm_qkv

  cvt_w_kernel<<<dim3(1024, 4), 256, 0, stream>>>(wq, wk, wv, wo, wqb, wkb, wvb, wob);
  conv3_kernel<<<4096, 256, 0, stream>>>(x, dwq_w, dwq_b, dwk_w, dwk_b, dwv_w, dwv_b, cq, ck, cv);
  gemm_qkv_kernel<<<dim3(8, 32, 3), 256, 0, stream>>>(cq, ck, cv, wqb, wkb, wvb, bq, bk, bv, qd, kd, vtb);
  attn_kernel<<<512, 256, 0, stream>>>(qd, kd, vtb, attn_out);
  gemm_out_kernel<<<dim3(8, 32), 256, 0, stream>>>(attn_out, wob, bo, out);
}